// Round 5
// baseline (1802.634 us; speedup 1.0000x reference)
//
#include <hip/hip_runtime.h>
#include <hip/hip_bf16.h>
#include <cstdint>

#define NT   900
#define EMB  1152
#define NH   16
#define DHD  72
#define DHH  36
#define DHP  96      // padded head dim (3*32)
#define KVW  928     // vt row width (unchanged layout)
#define NL   6
#define FFD  4608
#define MHD  4608
#define OUTD 2048
#define NM   225

typedef __attribute__((ext_vector_type(8))) short short8;
typedef __attribute__((ext_vector_type(4))) float f32x4;

__device__ __forceinline__ ushort f2bf(float f) {
    uint32_t u = __float_as_uint(f);
    uint32_t r = u + 0x7FFF + ((u >> 16) & 1);
    return (ushort)(r >> 16);
}
__device__ __forceinline__ float gelu_f(float x) {
    return 0.5f * x * (1.0f + tanhf(0.7978845608f * (x + 0.044715f * x * x * x)));
}

// ---------------- patch extraction: pixels -> bf16 [900, 1536] ----------------
__global__ __launch_bounds__(256) void k_patch(const float* __restrict__ pix,
                                               ushort* __restrict__ xp) {
    int idx = blockIdx.x * 256 + threadIdx.x;
    if (idx >= NT * 1536) return;
    int t = idx / 1536, f = idx - t * 1536;
    int mw = t & 1, mh = (t >> 1) & 1;
    int tq = t >> 2;
    int jj = tq % 15, ii = tq / 15;
    int pw = f & 15, ph = (f >> 4) & 15, c = f >> 9;
    int Hi = (ii * 2 + mh) * 16 + ph;
    int Wi = (jj * 2 + mw) * 16 + pw;
    float p = pix[((size_t)c * 480 + Hi) * 480 + Wi];
    xp[idx] = f2bf((p - 127.5f) * (1.0f / 127.5f));
}

// ---------------- layernorm f32 in -> bf16 out, one block per row ----------------
__global__ __launch_bounds__(256) void k_ln(const float* __restrict__ x,
                                            const float* __restrict__ w,
                                            const float* __restrict__ b,
                                            ushort* __restrict__ y, int C) {
    int row = blockIdx.x;
    int tid = threadIdx.x;
    const float* xr = x + (size_t)row * C;
    float s = 0.f, ss = 0.f;
    for (int c = tid; c < C; c += 256) { float v = xr[c]; s += v; ss += v * v; }
    for (int off = 32; off; off >>= 1) {
        s  += __shfl_down(s,  off, 64);
        ss += __shfl_down(ss, off, 64);
    }
    __shared__ float rs[4], rss[4];
    int wid = tid >> 6, lane = tid & 63;
    if (lane == 0) { rs[wid] = s; rss[wid] = ss; }
    __syncthreads();
    float S  = rs[0] + rs[1] + rs[2] + rs[3];
    float SS = rss[0] + rss[1] + rss[2] + rss[3];
    float mu  = S / C;
    float var = SS / C - mu * mu;
    float inv = rsqrtf(var + 1e-6f);
    ushort* yr = y + (size_t)row * C;
    for (int c = tid; c < C; c += 256) yr[c] = f2bf((xr[c] - mu) * inv * w[c] + b[c]);
}

// ---------------- dense MFMA GEMM, BK=64, reg-prefetch, optional split-K ----
template <int ACT, int OBF16, int SPLIT>
__global__ __launch_bounds__(256) void k_gsk(const ushort* __restrict__ A,
                                             const float* __restrict__ W,
                                             const float* __restrict__ bias,
                                             const float* __restrict__ res,
                                             void* __restrict__ Cp,
                                             float* __restrict__ part,
                                             int M, int N, int K, int S) {
    __shared__ __align__(16) ushort As[64 * 72];
    __shared__ __align__(16) ushort Bs[64 * 72];
    int tid = threadIdx.x;
    int row0 = blockIdx.x * 64, col0 = blockIdx.y * 64;
    int z = blockIdx.z;
    int Kc = K / S;              // multiple of 64
    int kbeg = z * Kc;
    int steps = Kc >> 6;

    int srow = tid >> 2;
    int scol = (tid & 3) << 4;   // 16-elem units
    int ar = row0 + srow; if (ar > M - 1) ar = M - 1;
    int wr = col0 + srow;
    const ushort* aptr = A + (size_t)ar * K + kbeg + scol;
    const float*  wptr = W + (size_t)wr * K + kbeg + scol;
    ushort* asd = &As[srow * 72 + scol];
    ushort* bsd = &Bs[srow * 72 + scol];

    uint4 ra0, ra1;
    float4 rw0, rw1, rw2, rw3;
#define LOADCHUNK(s)                                                     \
    { const ushort* p = aptr + ((s) << 6);                               \
      ra0 = *(const uint4*)p; ra1 = *(const uint4*)(p + 8);              \
      const float* q = wptr + ((s) << 6);                                \
      rw0 = *(const float4*)q;       rw1 = *(const float4*)(q + 4);      \
      rw2 = *(const float4*)(q + 8); rw3 = *(const float4*)(q + 12); }

    int lane = tid & 63, wid = tid >> 6;
    int wrr = (wid >> 1) * 32, wcc = (wid & 1) * 32;
    int fr = lane & 15, kg8 = (lane >> 4) << 3;

    f32x4 acc[2][2] = {};
    LOADCHUNK(0);
    for (int s = 0; s < steps; ++s) {
        __syncthreads();
        *(uint4*)asd = ra0; *(uint4*)(asd + 8) = ra1;
        ushort wa[8] = { f2bf(rw0.x), f2bf(rw0.y), f2bf(rw0.z), f2bf(rw0.w),
                         f2bf(rw1.x), f2bf(rw1.y), f2bf(rw1.z), f2bf(rw1.w) };
        ushort wb[8] = { f2bf(rw2.x), f2bf(rw2.y), f2bf(rw2.z), f2bf(rw2.w),
                         f2bf(rw3.x), f2bf(rw3.y), f2bf(rw3.z), f2bf(rw3.w) };
        *(uint4*)bsd = *(const uint4*)wa; *(uint4*)(bsd + 8) = *(const uint4*)wb;
        if (s + 1 < steps) LOADCHUNK(s + 1);
        __syncthreads();
#pragma unroll
        for (int j = 0; j < 2; ++j) {
            int ko = j * 32 + kg8;
            short8 a0 = *(const short8*)&As[(wrr + fr) * 72 + ko];
            short8 a1 = *(const short8*)&As[(wrr + 16 + fr) * 72 + ko];
            short8 b0 = *(const short8*)&Bs[(wcc + fr) * 72 + ko];
            short8 b1 = *(const short8*)&Bs[(wcc + 16 + fr) * 72 + ko];
            acc[0][0] = __builtin_amdgcn_mfma_f32_16x16x32_bf16(a0, b0, acc[0][0], 0, 0, 0);
            acc[0][1] = __builtin_amdgcn_mfma_f32_16x16x32_bf16(a0, b1, acc[0][1], 0, 0, 0);
            acc[1][0] = __builtin_amdgcn_mfma_f32_16x16x32_bf16(a1, b0, acc[1][0], 0, 0, 0);
            acc[1][1] = __builtin_amdgcn_mfma_f32_16x16x32_bf16(a1, b1, acc[1][1], 0, 0, 0);
        }
    }
#undef LOADCHUNK

#pragma unroll
    for (int fi = 0; fi < 2; fi++)
#pragma unroll
        for (int fj = 0; fj < 2; fj++)
#pragma unroll
            for (int r = 0; r < 4; r++) {
                int row = row0 + wrr + fi * 16 + (lane >> 4) * 4 + r;
                int col = col0 + wcc + fj * 16 + fr;
                if (row < M) {
                    if (SPLIT) {
                        part[((size_t)z * M + row) * N + col] = acc[fi][fj][r];
                    } else {
                        float v = acc[fi][fj][r] + bias[col];
                        if (res) v += res[(size_t)row * N + col];
                        if (ACT == 1) v = gelu_f(v);
                        if (OBF16) ((ushort*)Cp)[(size_t)row * N + col] = f2bf(v);
                        else       ((float*)Cp)[(size_t)row * N + col] = v;
                    }
                }
            }
}

// ---------------- split-K fixup ----------------
template <int ACT, int OBF16>
__global__ __launch_bounds__(256) void k_fix(const float* __restrict__ part,
                                             const float* __restrict__ bias,
                                             const float* __restrict__ res,
                                             void* __restrict__ Cp,
                                             int M, int N, int S) {
    size_t idx = (size_t)blockIdx.x * 256 + threadIdx.x;
    size_t total = (size_t)M * N / 4;
    if (idx >= total) return;
    size_t e = idx * 4;
    int row = (int)(e / N), col = (int)(e - (size_t)row * N);
    float4 v = *(const float4*)(part + e);
    for (int s = 1; s < S; ++s) {
        const float4 p = *(const float4*)(part + (size_t)s * M * N + e);
        v.x += p.x; v.y += p.y; v.z += p.z; v.w += p.w;
    }
    const float4 bi = *(const float4*)(bias + col);
    v.x += bi.x; v.y += bi.y; v.z += bi.z; v.w += bi.w;
    if (res) {
        const float4 rr = *(const float4*)(res + e);
        v.x += rr.x; v.y += rr.y; v.z += rr.z; v.w += rr.w;
    }
    if (ACT == 1) { v.x = gelu_f(v.x); v.y = gelu_f(v.y); v.z = gelu_f(v.z); v.w = gelu_f(v.w); }
    if (OBF16) {
        ushort o[4] = { f2bf(v.x), f2bf(v.y), f2bf(v.z), f2bf(v.w) };
        *(uint2*)((ushort*)Cp + e) = *(const uint2*)o;
    } else {
        *(float4*)((float*)Cp + e) = v;
    }
}

// ---------------- qkv f32 [900,3456] -> rope(q),rope(k) bf16 [16,900,96], v^T bf16 [16,96,928]
__global__ __launch_bounds__(256) void k_rope(const float* __restrict__ qkv,
                                              const float* __restrict__ cs,
                                              const float* __restrict__ sn,
                                              ushort* __restrict__ q,
                                              ushort* __restrict__ k,
                                              ushort* __restrict__ vt) {
    int idx = blockIdx.x * 256 + threadIdx.x;
    if (idx >= NT * NH * DHP) return;
    int t = idx / (NH * DHP);
    int rem = idx - t * (NH * DHP);
    int h = rem / DHP, d = rem - h * DHP;
    size_t oi = ((size_t)h * NT + t) * DHP + d;
    if (d < DHD) {
        const float* base = qkv + (size_t)t * 3 * EMB;
        float c = cs[t * DHD + d], s = sn[t * DHD + d];
        int   d2 = (d < DHH) ? d + DHH : d - DHH;
        float sg = (d < DHH) ? -1.f : 1.f;
        int e = h * DHD + d;
        float qv = base[e] * c + sg * base[h * DHD + d2] * s;
        float kv = base[EMB + e] * c + sg * base[EMB + h * DHD + d2] * s;
        q[oi] = f2bf(qv);
        k[oi] = f2bf(kv);
        vt[((size_t)h * DHP + d) * KVW + t] = f2bf(base[2 * EMB + e]);
    } else {
        q[oi] = 0;
        k[oi] = 0;
    }
}

// ---------------- fused flash attention ----------------
// grid (15 q-tiles, 16 heads), 256 threads (4 waves x 16 q rows).
// q/k: [h][900][96] bf16 (d 72..95 zero). vt: [h][96][928] bf16.
// out: ob[900][1152] bf16.
__global__ __launch_bounds__(256) void k_fa(const ushort* __restrict__ qg,
                                            const ushort* __restrict__ kg,
                                            const ushort* __restrict__ vg,
                                            ushort* __restrict__ ob) {
    __shared__ __align__(16) ushort Qs[64 * 104];
    __shared__ __align__(16) ushort Ks[64 * 104];
    __shared__ __align__(16) ushort Vs[80 * 76];
    __shared__ __align__(16) ushort Ps[4][16 * 76];

    const int h  = blockIdx.y;
    const int q0 = blockIdx.x * 64;
    const int tid = threadIdx.x;
    const int lane = tid & 63, w = tid >> 6;
    const int fr = lane & 15, g = lane >> 4;

    const ushort* qh = qg + (size_t)h * (NT * DHP);
    const ushort* kh = kg + (size_t)h * (NT * DHP);
    const ushort* vh = vg + (size_t)h * (DHP * KVW);

    // stage Q tile (64 x 96) once
    for (int i = tid; i < 768; i += 256) {
        int row = i / 12, cj = i % 12;
        int gr = q0 + row; if (gr > NT - 1) gr = NT - 1;
        *(uint4*)&Qs[row * 104 + cj * 8] = *(const uint4*)(qh + (size_t)gr * DHP + cj * 8);
    }
    __syncthreads();
    short8 aq[3];
#pragma unroll
    for (int ks = 0; ks < 3; ++ks)
        aq[ks] = *(const short8*)&Qs[(w * 16 + fr) * 104 + ks * 32 + g * 8];

    uint4 rk[3], rv[3];
    auto loadKV = [&](int s) {
        int k0 = s * 64;
#pragma unroll
        for (int j = 0; j < 3; ++j) {
            int i = tid + j * 256;
            int row = i / 12, cj = i % 12;
            int gr = k0 + row; if (gr > NT - 1) gr = NT - 1;
            rk[j] = *(const uint4*)(kh + (size_t)gr * DHP + cj * 8);
        }
#pragma unroll
        for (int j = 0; j < 3; ++j) {
            int i = tid + j * 256;
            if (i < 640) {
                int row = i >> 3, cj = i & 7;
                int gc = k0 + cj * 8; if (gc > KVW - 8) gc = KVW - 8;
                rv[j] = *(const uint4*)(vh + (size_t)row * KVW + gc);
            }
        }
    };
    auto writeKV = [&]() {
#pragma unroll
        for (int j = 0; j < 3; ++j) {
            int i = tid + j * 256;
            int row = i / 12, cj = i % 12;
            *(uint4*)&Ks[row * 104 + cj * 8] = rk[j];
        }
#pragma unroll
        for (int j = 0; j < 3; ++j) {
            int i = tid + j * 256;
            if (i < 640) {
                int row = i >> 3, cj = i & 7;
                *(uint4*)&Vs[row * 76 + cj * 8] = rv[j];
            }
        }
    };

    float m[4] = { -1e30f, -1e30f, -1e30f, -1e30f };
    float lsum[4] = {};
    f32x4 o[5] = {};
    ushort* pw = &Ps[w][0];

    loadKV(0);
    for (int s = 0; s < 15; ++s) {
        __syncthreads();
        writeKV();
        if (s + 1 < 15) loadKV(s + 1);
        __syncthreads();
        // S tile: C[q16][k64], lane: k = nt*16+fr, q = g*4+r
        f32x4 sc[4] = {};
#pragma unroll
        for (int nt = 0; nt < 4; ++nt)
#pragma unroll
            for (int ks = 0; ks < 3; ++ks) {
                short8 b = *(const short8*)&Ks[(nt * 16 + fr) * 104 + ks * 32 + g * 8];
                sc[nt] = __builtin_amdgcn_mfma_f32_16x16x32_bf16(aq[ks], b, sc[nt], 0, 0, 0);
            }
        int kbase = s * 64;
        if (kbase + 64 > NT) {
#pragma unroll
            for (int nt = 0; nt < 4; ++nt)
                if (kbase + nt * 16 + fr >= NT) {
                    sc[nt][0] = -1e30f; sc[nt][1] = -1e30f;
                    sc[nt][2] = -1e30f; sc[nt][3] = -1e30f;
                }
        }
        // online softmax per accumulator row r (q = g*4+r)
#pragma unroll
        for (int r = 0; r < 4; ++r) {
            float tm = fmaxf(fmaxf(sc[0][r], sc[1][r]), fmaxf(sc[2][r], sc[3][r]));
#pragma unroll
            for (int off = 1; off < 16; off <<= 1) tm = fmaxf(tm, __shfl_xor(tm, off, 64));
            float mn = fmaxf(m[r], tm);
            float scale = __expf(m[r] - mn);
            m[r] = mn;
            float ps = 0.f;
#pragma unroll
            for (int nt = 0; nt < 4; ++nt) {
                float p = __expf(sc[nt][r] - mn);
                ps += p;
                pw[(g * 4 + r) * 76 + nt * 16 + fr] = f2bf(p);
            }
#pragma unroll
            for (int off = 1; off < 16; off <<= 1) ps += __shfl_xor(ps, off, 64);
            lsum[r] = lsum[r] * scale + ps;
#pragma unroll
            for (int dt = 0; dt < 5; ++dt) o[dt][r] *= scale;
        }
        // PV: O[q16][d80] += P[q16][k64] @ V[k64][d80]
#pragma unroll
        for (int kt = 0; kt < 2; ++kt) {
            short8 a = *(const short8*)&pw[fr * 76 + kt * 32 + g * 8];
#pragma unroll
            for (int dt = 0; dt < 5; ++dt) {
                short8 b = *(const short8*)&Vs[(dt * 16 + fr) * 76 + kt * 32 + g * 8];
                o[dt] = __builtin_amdgcn_mfma_f32_16x16x32_bf16(a, b, o[dt], 0, 0, 0);
            }
        }
    }
    float inv[4];
#pragma unroll
    for (int r = 0; r < 4; ++r) inv[r] = 1.f / lsum[r];
#pragma unroll
    for (int dt = 0; dt < 5; ++dt)
#pragma unroll
        for (int r = 0; r < 4; ++r) {
            int q = q0 + w * 16 + g * 4 + r;
            int d = dt * 16 + fr;
            if (q < NT && d < DHD)
                ob[(size_t)q * EMB + h * DHD + d] = f2bf(o[dt][r] * inv[r]);
        }
}

extern "C" void kernel_launch(void* const* d_in, const int* in_sizes, int n_in,
                              void* d_out, int out_size, void* d_ws, size_t ws_size,
                              hipStream_t stream) {
    const float* pix     = (const float*)d_in[0];
    const float* patch_w = (const float*)d_in[1];
    const float* patch_b = (const float*)d_in[2];
    const float* pos_emb = (const float*)d_in[3];
    const float* cosb    = (const float*)d_in[4];
    const float* sinb    = (const float*)d_in[5];
    const float* ln1_w   = (const float*)d_in[6];
    const float* ln1_b   = (const float*)d_in[7];
    const float* qkv_w   = (const float*)d_in[8];
    const float* qkv_b   = (const float*)d_in[9];
    const float* proj_w  = (const float*)d_in[10];
    const float* proj_b  = (const float*)d_in[11];
    const float* ln2_w   = (const float*)d_in[12];
    const float* ln2_b   = (const float*)d_in[13];
    const float* fc1_w   = (const float*)d_in[14];
    const float* fc1_b   = (const float*)d_in[15];
    const float* fc2_w   = (const float*)d_in[16];
    const float* fc2_b   = (const float*)d_in[17];
    const float* dsn_w   = (const float*)d_in[18];
    const float* dsn_b   = (const float*)d_in[19];
    const float* ds1_w   = (const float*)d_in[20];
    const float* ds1_b   = (const float*)d_in[21];
    const float* ds2_w   = (const float*)d_in[22];
    const float* ds2_b   = (const float*)d_in[23];
    const float* mn_w    = (const float*)d_in[24];
    const float* mn_b    = (const float*)d_in[25];
    const float* mf1_w   = (const float*)d_in[26];
    const float* mf1_b   = (const float*)d_in[27];
    const float* mf2_w   = (const float*)d_in[28];
    const float* mf2_b   = (const float*)d_in[29];
    float* out = (float*)d_out;

    // ---- workspace carve ----
    float* wsf = (float*)d_ws;
    size_t off = 0;
    auto af = [&](size_t n) { float* p = wsf + off; off += (n + 3) & ~(size_t)3; return p; };
    float* h    = af((size_t)NT * EMB);
    float* qkv  = af((size_t)NT * 3 * EMB);
    float* part = af((size_t)4 * NT * EMB);       // split-K partials (max S=4, N<=1152 for M=900; 4*225*4608 equal)
    ushort* wsh = (ushort*)(wsf + off);
    size_t hoff = 0;
    auto ah = [&](size_t n) { ushort* p = wsh + hoff; hoff += (n + 7) & ~(size_t)7; return p; };
    ushort* hn  = ah((size_t)NT * EMB);
    ushort* qb  = ah((size_t)NH * NT * DHP);
    ushort* kb  = ah((size_t)NH * NT * DHP);
    ushort* vt  = ah((size_t)NH * DHP * KVW);
    ushort* ob  = ah((size_t)NT * EMB);
    ushort* t1  = ah((size_t)NT * FFD);
    ushort* xp  = t1;

    const int MB  = (NT + 63) / 64;   // 15
    const int MBm = (NM + 63) / 64;   // 4
    auto fixg = [](int M, int N) { return dim3(((size_t)M * N / 4 + 255) / 256); };

    k_patch<<<dim3((NT * 1536 + 255) / 256), 256, 0, stream>>>(pix, xp);
    k_gsk<0, 0, 1><<<dim3(MB, EMB / 64, 2), 256, 0, stream>>>(
        xp, patch_w, nullptr, nullptr, nullptr, part, NT, EMB, 1536, 2);
    k_fix<0, 0><<<fixg(NT, EMB), 256, 0, stream>>>(part, patch_b, pos_emb, h, NT, EMB, 2);

    for (int l = 0; l < NL; ++l) {
        k_ln<<<NT, 256, 0, stream>>>(h, ln1_w + l * EMB, ln1_b + l * EMB, hn, EMB);
        k_gsk<0, 0, 0><<<dim3(MB, 3 * EMB / 64, 1), 256, 0, stream>>>(
            hn, qkv_w + (size_t)l * 3 * EMB * EMB, qkv_b + l * 3 * EMB, nullptr, qkv,
            nullptr, NT, 3 * EMB, EMB, 1);
        k_rope<<<dim3((NT * NH * DHP + 255) / 256), 256, 0, stream>>>(
            qkv, cosb, sinb, qb, kb, vt);
        k_fa<<<dim3(MB, NH), 256, 0, stream>>>(qb, kb, vt, ob);
        k_gsk<0, 0, 1><<<dim3(MB, EMB / 64, 3), 256, 0, stream>>>(
            ob, proj_w + (size_t)l * EMB * EMB, nullptr, nullptr, nullptr, part,
            NT, EMB, EMB, 3);
        k_fix<0, 0><<<fixg(NT, EMB), 256, 0, stream>>>(part, proj_b + l * EMB, h, h,
                                                       NT, EMB, 3);
        k_ln<<<NT, 256, 0, stream>>>(h, ln2_w + l * EMB, ln2_b + l * EMB, hn, EMB);
        k_gsk<1, 1, 0><<<dim3(MB, FFD / 64, 1), 256, 0, stream>>>(
            hn, fc1_w + (size_t)l * FFD * EMB, fc1_b + l * FFD, nullptr, t1,
            nullptr, NT, FFD, EMB, 1);
        k_gsk<0, 0, 1><<<dim3(MB, EMB / 64, 4), 256, 0, stream>>>(
            t1, fc2_w + (size_t)l * EMB * FFD, nullptr, nullptr, nullptr, part,
            NT, EMB, FFD, 4);
        k_fix<0, 0><<<fixg(NT, EMB), 256, 0, stream>>>(part, fc2_b + l * EMB, h, h,
                                                       NT, EMB, 4);
        if (l == 2 || l == 5) {
            int d = (l == 2) ? 0 : 1;
            k_ln<<<NM, 256, 0, stream>>>(h, dsn_w + d * MHD, dsn_b + d * MHD, hn, MHD);
            k_gsk<0, 0, 1><<<dim3(MBm, MHD / 64, 4), 256, 0, stream>>>(
                hn, ds1_w + (size_t)d * MHD * MHD, nullptr, nullptr, nullptr, part,
                NM, MHD, MHD, 4);
            k_fix<1, 1><<<fixg(NM, MHD), 256, 0, stream>>>(part, ds1_b + d * MHD,
                                                           nullptr, t1, NM, MHD, 4);
            k_gsk<0, 0, 1><<<dim3(MBm, OUTD / 64, 4), 256, 0, stream>>>(
                t1, ds2_w + (size_t)d * OUTD * MHD, nullptr, nullptr, nullptr, part,
                NM, OUTD, MHD, 4);
            k_fix<0, 0><<<fixg(NM, OUTD), 256, 0, stream>>>(
                part, ds2_b + d * OUTD, nullptr, out + (size_t)d * NM * OUTD,
                NM, OUTD, 4);
        }
    }
    // merger LN is over EMB=1152 per token (900 rows), THEN reshaped to [225][4608]
    k_ln<<<NT, 256, 0, stream>>>(h, mn_w, mn_b, hn, EMB);
    k_gsk<0, 0, 1><<<dim3(MBm, MHD / 64, 4), 256, 0, stream>>>(
        hn, mf1_w, nullptr, nullptr, nullptr, part, NM, MHD, MHD, 4);
    k_fix<1, 1><<<fixg(NM, MHD), 256, 0, stream>>>(part, mf1_b, nullptr, t1, NM, MHD, 4);
    k_gsk<0, 0, 1><<<dim3(MBm, OUTD / 64, 4), 256, 0, stream>>>(
        t1, mf2_w, nullptr, nullptr, nullptr, part, NM, OUTD, MHD, 4);
    k_fix<0, 0><<<fixg(NM, OUTD), 256, 0, stream>>>(
        part, mf2_b, nullptr, out + (size_t)2 * NM * OUTD, NM, OUTD, 4);
}